// Round 1
// baseline (237.316 us; speedup 1.0000x reference)
//
#include <hip/hip_runtime.h>

// Attention fwd: x@Wqkv^T -> flash attn -> @Wproj^T.  bf16 MFMA pipeline, fp32 accum.
// B=2 N=2048 C=768 H=12 Dh=64.

typedef __bf16 bf16;
typedef __attribute__((ext_vector_type(8))) __bf16 bf16x8;
typedef __attribute__((ext_vector_type(4))) __bf16 bf16x4;
typedef __attribute__((ext_vector_type(4))) float f32x4;

typedef __attribute__((address_space(1))) void gvoid;
typedef __attribute__((address_space(3))) void lvoid;

__device__ __forceinline__ void gload16(const void* g, void* l) {
  __builtin_amdgcn_global_load_lds((gvoid*)g, (lvoid*)l, 16, 0, 0);
}

// ---------------- fp32 -> bf16 conversion (x, W_qkv, W_proj) ----------------
__global__ __launch_bounds__(256) void cvt3(const float* __restrict__ x,
                                            const float* __restrict__ wq,
                                            const float* __restrict__ wp,
                                            bf16* __restrict__ xb,
                                            bf16* __restrict__ wqb,
                                            bf16* __restrict__ wpb) {
  const int N1 = 786432, N2 = 442368, N3 = 147456;  // float4 counts
  int i = blockIdx.x * 256 + threadIdx.x;
  const int stride = gridDim.x * 256;
  const int total = N1 + N2 + N3;
  for (; i < total; i += stride) {
    const float* src; bf16* dst; int j;
    if (i < N1)           { src = x;  dst = xb;  j = i; }
    else if (i < N1 + N2) { src = wq; dst = wqb; j = i - N1; }
    else                  { src = wp; dst = wpb; j = i - N1 - N2; }
    float4 v = ((const float4*)src)[j];
    bf16x4 o = { (bf16)v.x, (bf16)v.y, (bf16)v.z, (bf16)v.w };
    *(bf16x4*)(dst + (long)j * 4) = o;
  }
}

// ---------------- NT GEMM: C[M,N] = A[M,K] * B[N,K]^T, bf16 in, fp32 accum -----
// 128x128 tile, BK=32, 256 thr (4 waves 2x2), 16x16x32 bf16 MFMA.
// LDS linear dest for global_load_lds; bank-conflict XOR swizzle applied by
// pre-swizzling the GLOBAL source chunk (both-sides rule).
template <typename OutT>
__global__ __launch_bounds__(256) void gemm_nt(const bf16* __restrict__ A,
                                               const bf16* __restrict__ B,
                                               OutT* __restrict__ C,
                                               int K, int lda, int ldb, int ldc,
                                               int mtiles) {
  __shared__ __align__(16) char smem[32768];  // [buf][A 8K | B 8K] x2
  const int tid  = threadIdx.x;
  const int lane = tid & 63;
  const int w    = tid >> 6;
  const int wm   = w >> 1, wn = w & 1;
  const int m0   = (blockIdx.x % mtiles) * 128;
  const int n0   = (blockIdx.x / mtiles) * 128;
  const int nt   = K >> 5;

  f32x4 acc[4][4] = {};

  auto stage = [&](int buf, int t) {
    const int k0 = t << 5;
    char* sA = smem + buf * 16384;
    char* sB = sA + 8192;
#pragma unroll
    for (int i = 0; i < 2; ++i) {
      const int slot = i * 256 + tid;          // 512 chunks of 16B per operand
      const int row  = slot >> 2;              // [0,128)
      const int sc   = (slot & 3) ^ (row & 3); // pre-swizzled source chunk
      gload16(A + (long)(m0 + row) * lda + k0 + sc * 8, sA + slot * 16);
      gload16(B + (long)(n0 + row) * ldb + k0 + sc * 8, sB + slot * 16);
    }
  };

  auto compute = [&](int buf) {
    const char* sA = smem + buf * 16384;
    const char* sB = sA + 8192;
    const int c = lane >> 4;
    bf16x8 a[4], b[4];
#pragma unroll
    for (int mi = 0; mi < 4; ++mi) {
      const int row = wm * 64 + mi * 16 + (lane & 15);
      a[mi] = *(const bf16x8*)(sA + row * 64 + ((c ^ (row & 3)) << 4));
    }
#pragma unroll
    for (int ni = 0; ni < 4; ++ni) {
      const int row = wn * 64 + ni * 16 + (lane & 15);
      b[ni] = *(const bf16x8*)(sB + row * 64 + ((c ^ (row & 3)) << 4));
    }
#pragma unroll
    for (int mi = 0; mi < 4; ++mi)
#pragma unroll
      for (int ni = 0; ni < 4; ++ni)
        acc[mi][ni] = __builtin_amdgcn_mfma_f32_16x16x32_bf16(a[mi], b[ni], acc[mi][ni], 0, 0, 0);
  };

  stage(0, 0);
  __syncthreads();
  for (int t = 0; t < nt; ++t) {
    if (t + 1 < nt) stage((t + 1) & 1, t + 1);
    compute(t & 1);
    __syncthreads();
  }

  // C/D layout: col = lane&15, row = (lane>>4)*4 + reg  (m89-verified)
#pragma unroll
  for (int mi = 0; mi < 4; ++mi)
#pragma unroll
    for (int ni = 0; ni < 4; ++ni)
#pragma unroll
      for (int r = 0; r < 4; ++r) {
        const int row = m0 + wm * 64 + mi * 16 + (lane >> 4) * 4 + r;
        const int col = n0 + wn * 64 + ni * 16 + (lane & 15);
        C[(long)row * ldc + col] = (OutT)acc[mi][ni][r];
      }
}

// ---------------- flash attention fwd ----------------
// grid (32 qtiles, 24 bh); block 256 = 4 waves, wave owns 16 q-rows.
// Q,K fragments straight from global (cache-resident); V transposed into
// swizzled LDS; P re-layout via wave-private swizzled LDS.
__global__ __launch_bounds__(256) void attn_fwd(const bf16* __restrict__ qkv,
                                                bf16* __restrict__ O) {
  __shared__ __align__(16) char smem[16384];  // Vt[64][64] 8K | P[4][16][64] 8K
  char* Vt = smem;
  char* Pw = smem + 8192;

  const int tid  = threadIdx.x;
  const int lane = tid & 63;
  const int w    = tid >> 6;
  const int b    = blockIdx.y / 12;
  const int h    = blockIdx.y % 12;
  const int q0   = blockIdx.x * 64;
  const long base = (long)b * 2048 * 2304;
  const int h64  = h * 64;
  const int l15  = lane & 15;
  const int l4   = lane >> 4;

  // Q A-fragments: lane holds Q[row = l15][k = l4*8 .. +8] per 32-wide k chunk
  bf16x8 qf[2];
  {
    const long rq = base + (long)(q0 + w * 16 + l15) * 2304 + h64 + l4 * 8;
#pragma unroll
    for (int kk = 0; kk < 2; ++kk)
      qf[kk] = *(const bf16x8*)(qkv + rq + kk * 32);
  }

  float m[4], l[4];
  f32x4 o[4] = {};
#pragma unroll
  for (int r = 0; r < 4; ++r) { m[r] = -__builtin_inff(); l[r] = 0.f; }

  for (int kv0 = 0; kv0 < 2048; kv0 += 64) {
    __syncthreads();  // previous PV finished reading Vt

    // stage V transposed + swizzled: Vt[d][kv]; thread: kv = tid&63, d-blk = (tid>>6)*16
    {
      const int r  = tid & 63;
      const int dg = (tid >> 6) * 16;
      const bf16* vrow = qkv + base + (long)(kv0 + r) * 2304 + 1536 + h64 + dg;
      const bf16x8 v0 = *(const bf16x8*)(vrow);
      const bf16x8 v1 = *(const bf16x8*)(vrow + 8);
#pragma unroll
      for (int j = 0; j < 8; ++j) {
        const int d = dg + j;
        *(bf16*)(Vt + d * 128 + (((r >> 3) ^ (d & 7)) << 4) + (r & 7) * 2) = v0[j];
      }
#pragma unroll
      for (int j = 0; j < 8; ++j) {
        const int d = dg + 8 + j;
        *(bf16*)(Vt + d * 128 + (((r >> 3) ^ (d & 7)) << 4) + (r & 7) * 2) = v1[j];
      }
    }

    // S = Q K^T  (B-frag: B[k=d][col=kv] = K[kv][d], contiguous in K's row)
    f32x4 s[4] = {};
#pragma unroll
    for (int f = 0; f < 4; ++f) {
      const long kr = base + (long)(kv0 + f * 16 + l15) * 2304 + 768 + h64 + l4 * 8;
#pragma unroll
      for (int kk = 0; kk < 2; ++kk) {
        const bf16x8 bk = *(const bf16x8*)(qkv + kr + kk * 32);
        s[f] = __builtin_amdgcn_mfma_f32_16x16x32_bf16(qf[kk], bk, s[f], 0, 0, 0);
      }
    }
#pragma unroll
    for (int f = 0; f < 4; ++f)
#pragma unroll
      for (int r = 0; r < 4; ++r) s[f][r] *= 0.125f;  // SCALE = Dh^-0.5

    // online softmax; lane's rows = l4*4 + r, cols over (f, l15)
    float rmax[4], rsum[4], alpha[4];
#pragma unroll
    for (int r = 0; r < 4; ++r)
      rmax[r] = fmaxf(fmaxf(s[0][r], s[1][r]), fmaxf(s[2][r], s[3][r]));
#pragma unroll
    for (int off = 1; off < 16; off <<= 1)
#pragma unroll
      for (int r = 0; r < 4; ++r) rmax[r] = fmaxf(rmax[r], __shfl_xor(rmax[r], off));
#pragma unroll
    for (int r = 0; r < 4; ++r) {
      const float mn = fmaxf(m[r], rmax[r]);
      alpha[r] = __expf(m[r] - mn);
      m[r] = mn;
      rsum[r] = 0.f;
    }
#pragma unroll
    for (int f = 0; f < 4; ++f)
#pragma unroll
      for (int r = 0; r < 4; ++r) {
        const float p = __expf(s[f][r] - m[r]);
        s[f][r] = p;
        rsum[r] += p;
      }
#pragma unroll
    for (int off = 1; off < 16; off <<= 1)
#pragma unroll
      for (int r = 0; r < 4; ++r) rsum[r] += __shfl_xor(rsum[r], off);
#pragma unroll
    for (int r = 0; r < 4; ++r) l[r] = l[r] * alpha[r] + rsum[r];
#pragma unroll
    for (int fd = 0; fd < 4; ++fd)
#pragma unroll
      for (int r = 0; r < 4; ++r) o[fd][r] *= alpha[r];

    // P -> wave-private LDS (bf16, swizzled): P[q_row(16)][kv(64)]
#pragma unroll
    for (int f = 0; f < 4; ++f)
#pragma unroll
      for (int r = 0; r < 4; ++r) {
        const int row = l4 * 4 + r;
        const int cb  = (f * 16 + l15) * 2;
        *(bf16*)(Pw + w * 2048 + row * 128 + (((cb >> 4) ^ (row & 7)) << 4) + (cb & 15)) =
            (bf16)s[f][r];
      }

    __syncthreads();  // Vt visible to all waves; own P drained by barrier waitcnt

    // O += P V : A-frag from P LDS, B-frag from Vt LDS
#pragma unroll
    for (int kk = 0; kk < 2; ++kk) {
      const int c = kk * 4 + l4;
      const bf16x8 ap = *(const bf16x8*)(Pw + w * 2048 + l15 * 128 + ((c ^ (l15 & 7)) << 4));
#pragma unroll
      for (int fd = 0; fd < 4; ++fd) {
        const int d = fd * 16 + l15;
        const bf16x8 bv = *(const bf16x8*)(Vt + d * 128 + ((c ^ (d & 7)) << 4));
        o[fd] = __builtin_amdgcn_mfma_f32_16x16x32_bf16(ap, bv, o[fd], 0, 0, 0);
      }
    }
  }

  // normalize + store bf16 attention output at [token][h*64 + d]
  float invl[4];
#pragma unroll
  for (int r = 0; r < 4; ++r) invl[r] = 1.f / l[r];
#pragma unroll
  for (int fd = 0; fd < 4; ++fd)
#pragma unroll
    for (int r = 0; r < 4; ++r) {
      const int row = q0 + w * 16 + l4 * 4 + r;
      O[((long)(b * 2048 + row)) * 768 + h64 + fd * 16 + l15] = (bf16)(o[fd][r] * invl[r]);
    }
}

// ---------------- launch ----------------
extern "C" void kernel_launch(void* const* d_in, const int* in_sizes, int n_in,
                              void* d_out, int out_size, void* d_ws, size_t ws_size,
                              hipStream_t stream) {
  const float* x  = (const float*)d_in[0];
  const float* wq = (const float*)d_in[1];
  const float* wp = (const float*)d_in[2];
  float* out = (float*)d_out;
  char* ws = (char*)d_ws;

  // ws layout (bytes): xb 6.29MB | wqb 3.54MB | wpb 1.18MB | qkvb 18.87MB | ob 6.29MB
  bf16* xb   = (bf16*)(ws + 0);
  bf16* wqb  = (bf16*)(ws + 6291456);
  bf16* wpb  = (bf16*)(ws + 9830400);
  bf16* qkvb = (bf16*)(ws + 11010048);
  bf16* ob   = (bf16*)(ws + 29884416);

  cvt3<<<dim3(1024), dim3(256), 0, stream>>>(x, wq, wp, xb, wqb, wpb);
  // qkv = x @ Wqkv^T : M=4096 N=2304 K=768
  gemm_nt<bf16><<<dim3(576), dim3(256), 0, stream>>>(xb, wqb, qkvb, 768, 768, 768, 2304, 32);
  attn_fwd<<<dim3(32, 24), dim3(256), 0, stream>>>(qkvb, ob);
  // out = attn_out @ Wproj^T : M=4096 N=768 K=768, fp32 out
  gemm_nt<float><<<dim3(192), dim3(256), 0, stream>>>(ob, wpb, out, 768, 768, 768, 768, 32);
}

// Round 3
// 217.801 us; speedup vs baseline: 1.0896x; 1.0896x over previous
//
#include <hip/hip_runtime.h>

// Attention fwd: x@Wqkv^T -> flash attn -> @Wproj^T.  bf16 MFMA pipeline, fp32 accum.
// B=2 N=2048 C=768 H=12 Dh=64.

typedef __bf16 bf16;
typedef __attribute__((ext_vector_type(8))) __bf16 bf16x8;
typedef __attribute__((ext_vector_type(4))) __bf16 bf16x4;
typedef __attribute__((ext_vector_type(4))) float f32x4;

typedef __attribute__((address_space(1))) void gvoid;
typedef __attribute__((address_space(3))) void lvoid;

__device__ __forceinline__ void gload16(const void* g, void* l) {
  __builtin_amdgcn_global_load_lds((gvoid*)g, (lvoid*)l, 16, 0, 0);
}

// ---------------- fp32 -> bf16 conversion (x, W_qkv, W_proj) ----------------
__global__ __launch_bounds__(256) void cvt3(const float* __restrict__ x,
                                            const float* __restrict__ wq,
                                            const float* __restrict__ wp,
                                            bf16* __restrict__ xb,
                                            bf16* __restrict__ wqb,
                                            bf16* __restrict__ wpb) {
  const int N1 = 786432, N2 = 442368, N3 = 147456;  // float4 counts
  int i = blockIdx.x * 256 + threadIdx.x;
  const int stride = gridDim.x * 256;
  const int total = N1 + N2 + N3;
  for (; i < total; i += stride) {
    const float* src; bf16* dst; int j;
    if (i < N1)           { src = x;  dst = xb;  j = i; }
    else if (i < N1 + N2) { src = wq; dst = wqb; j = i - N1; }
    else                  { src = wp; dst = wpb; j = i - N1 - N2; }
    float4 v = ((const float4*)src)[j];
    bf16x4 o = { (bf16)v.x, (bf16)v.y, (bf16)v.z, (bf16)v.w };
    *(bf16x4*)(dst + (long)j * 4) = o;
  }
}

// ---------------- NT GEMM: C[M,N] = A[M,K] * B[N,K]^T, bf16 in, fp32 accum -----
template <typename OutT>
__global__ __launch_bounds__(256) void gemm_nt(const bf16* __restrict__ A,
                                               const bf16* __restrict__ B,
                                               OutT* __restrict__ C,
                                               int K, int lda, int ldb, int ldc,
                                               int mtiles) {
  __shared__ __align__(16) char smem[32768];  // [buf][A 8K | B 8K] x2
  const int tid  = threadIdx.x;
  const int lane = tid & 63;
  const int w    = tid >> 6;
  const int wm   = w >> 1, wn = w & 1;
  const int m0   = (blockIdx.x % mtiles) * 128;
  const int n0   = (blockIdx.x / mtiles) * 128;
  const int nt   = K >> 5;

  f32x4 acc[4][4] = {};

  auto stage = [&](int buf, int t) {
    const int k0 = t << 5;
    char* sA = smem + buf * 16384;
    char* sB = sA + 8192;
#pragma unroll
    for (int i = 0; i < 2; ++i) {
      const int slot = i * 256 + tid;          // 512 chunks of 16B per operand
      const int row  = slot >> 2;              // [0,128)
      const int sc   = (slot & 3) ^ (row & 3); // pre-swizzled source chunk
      gload16(A + (long)(m0 + row) * lda + k0 + sc * 8, sA + slot * 16);
      gload16(B + (long)(n0 + row) * ldb + k0 + sc * 8, sB + slot * 16);
    }
  };

  auto compute = [&](int buf) {
    const char* sA = smem + buf * 16384;
    const char* sB = sA + 8192;
    const int c = lane >> 4;
    bf16x8 a[4], b[4];
#pragma unroll
    for (int mi = 0; mi < 4; ++mi) {
      const int row = wm * 64 + mi * 16 + (lane & 15);
      a[mi] = *(const bf16x8*)(sA + row * 64 + ((c ^ (row & 3)) << 4));
    }
#pragma unroll
    for (int ni = 0; ni < 4; ++ni) {
      const int row = wn * 64 + ni * 16 + (lane & 15);
      b[ni] = *(const bf16x8*)(sB + row * 64 + ((c ^ (row & 3)) << 4));
    }
#pragma unroll
    for (int mi = 0; mi < 4; ++mi)
#pragma unroll
      for (int ni = 0; ni < 4; ++ni)
        acc[mi][ni] = __builtin_amdgcn_mfma_f32_16x16x32_bf16(a[mi], b[ni], acc[mi][ni], 0, 0, 0);
  };

  stage(0, 0);
  __syncthreads();
  for (int t = 0; t < nt; ++t) {
    if (t + 1 < nt) stage((t + 1) & 1, t + 1);
    compute(t & 1);
    __syncthreads();
  }

#pragma unroll
  for (int mi = 0; mi < 4; ++mi)
#pragma unroll
    for (int ni = 0; ni < 4; ++ni)
#pragma unroll
      for (int r = 0; r < 4; ++r) {
        const int row = m0 + wm * 64 + mi * 16 + (lane >> 4) * 4 + r;
        const int col = n0 + wn * 64 + ni * 16 + (lane & 15);
        C[(long)row * ldc + col] = (OutT)acc[mi][ni][r];
      }
}

// ---------------- flash attention fwd (swapped-QK^T, in-register P) ----------
// grid (32 qtiles, 24 bh); block 256 = 4 waves, wave owns 16 q-rows.
// S^T = K·Q^T so each lane owns one q-column of scores (2-shuffle softmax).
// P stays in registers (permuted-k fragment mapping shared by A and B sides).
// V: reg-staged global loads (issued early), XOR-swizzled scatter transpose
// into double-buffered LDS (round-1-verified pattern), b64 B-frag reads.
__global__ __launch_bounds__(256, 3) void attn_fwd(const bf16* __restrict__ qkv,
                                                   bf16* __restrict__ O) {
  __shared__ __align__(16) char Vs[16384];  // 2 bufs x Vt[64][64] swizzled
  const int tid  = threadIdx.x;
  const int lane = tid & 63;
  const int w    = tid >> 6;
  const int l15  = lane & 15;
  const int l4   = lane >> 4;
  const int b    = blockIdx.y / 12;
  const int h    = blockIdx.y % 12;
  const int q0   = blockIdx.x * 64;
  const long base = (long)b * 2048 * 2304;
  const int h64  = h * 64;
  const long VSTEP = 64 * 2304;

  // Q fragments, pre-scaled by SCALE=0.125
  bf16x8 qf[2];
  {
    const bf16* qp = qkv + base + (long)(q0 + w * 16 + l15) * 2304 + h64 + l4 * 8;
#pragma unroll
    for (int kk = 0; kk < 2; ++kk) {
      bf16x8 t = *(const bf16x8*)(qp + kk * 32);
#pragma unroll
      for (int j = 0; j < 8; ++j) qf[kk][j] = (bf16)((float)t[j] * 0.125f);
    }
  }

  // K row pointers (A-fragments straight from global; L2/L3-resident)
  const bf16* kp[4];
#pragma unroll
  for (int f = 0; f < 4; ++f)
    kp[f] = qkv + base + (long)(f * 16 + l15) * 2304 + 768 + h64 + l4 * 8;

  // V stage: thread loads row kv = lane, d-block dg = w*16 (16 bf16 = 2 x b128)
  const int dg = w * 16;
  const bf16* vp = qkv + base + (long)lane * 2304 + 1536 + h64 + dg;

  // scatter-write a 16-elem V row chunk into swizzled Vt[d][kv]
  auto vt_write = [&](char* W, const bf16x8& v0, const bf16x8& v1) {
    const int r = lane;
    const int rc = (r >> 3);
    const int ro = (r & 7) * 2;
#pragma unroll
    for (int j = 0; j < 8; ++j) {
      const int d = dg + j;
      *(bf16*)(W + d * 128 + ((rc ^ (d & 7)) << 4) + ro) = v0[j];
    }
#pragma unroll
    for (int j = 0; j < 8; ++j) {
      const int d = dg + 8 + j;
      *(bf16*)(W + d * 128 + ((rc ^ (d & 7)) << 4) + ro) = v1[j];
    }
  };

  float m = -1e30f, lsum = 0.f;
  f32x4 o[4] = {};

  // prologue: stage V tile 0 into buf 0
  {
    bf16x8 v0 = *(const bf16x8*)(vp);
    bf16x8 v1 = *(const bf16x8*)(vp + 8);
    vp += VSTEP;
    vt_write(Vs, v0, v1);
  }
  __syncthreads();

  for (int t = 0; t < 32; ++t) {
    const int buf = t & 1;

    // (a) issue next V tile's global loads early (used after PV)
    bf16x8 nv0, nv1;
    if (t < 31) {
      nv0 = *(const bf16x8*)(vp);
      nv1 = *(const bf16x8*)(vp + 8);
      vp += VSTEP;
    }

    // (b) S^T = K Q^T : rows = kv (l4*4+r per 16-frag f), cols = q (l15)
    f32x4 s[4];
#pragma unroll
    for (int f = 0; f < 4; ++f) {
      bf16x8 k0 = *(const bf16x8*)(kp[f]);
      bf16x8 k1 = *(const bf16x8*)(kp[f] + 32);
      f32x4 acc = {};
      acc = __builtin_amdgcn_mfma_f32_16x16x32_bf16(k0, qf[0], acc, 0, 0, 0);
      acc = __builtin_amdgcn_mfma_f32_16x16x32_bf16(k1, qf[1], acc, 0, 0, 0);
      s[f] = acc;
      kp[f] += VSTEP;
    }

    // (c) softmax: tile max for this lane's q (=l15)
    float tm = s[0][0];
#pragma unroll
    for (int f = 0; f < 4; ++f)
#pragma unroll
      for (int r = 0; r < 4; ++r) tm = fmaxf(tm, s[f][r]);
    tm = fmaxf(tm, __shfl_xor(tm, 16));
    tm = fmaxf(tm, __shfl_xor(tm, 32));

    // defer-max: rescale only when tile max outgrows running max by >8
    if (__any(tm > m + 8.f)) {
      const float mn = fmaxf(m, tm);
      const float alpha = __expf(m - mn);
      m = mn;
      lsum *= alpha;
      f32x4 av;
#pragma unroll
      for (int r = 0; r < 4; ++r) av[r] = __shfl(alpha, l4 * 4 + r);
#pragma unroll
      for (int fd = 0; fd < 4; ++fd) o[fd] *= av;
    }

    // p = exp(s - m); lane-local partial row-sum
    float rs = 0.f;
#pragma unroll
    for (int f = 0; f < 4; ++f)
#pragma unroll
      for (int r = 0; r < 4; ++r) {
        const float p = __expf(s[f][r] - m);
        s[f][r] = p;
        rs += p;
      }

    // P A-fragments in-register (k-slot j of mfma kk -> kv = (kk*2+(j>>2))*16 + l4*4 + (j&3))
    bf16x8 pa[2];
#pragma unroll
    for (int kk = 0; kk < 2; ++kk)
#pragma unroll
      for (int j = 0; j < 8; ++j)
        pa[kk][j] = (bf16)s[kk * 2 + (j >> 2)][j & 3];

    // (e) O += P V : B-frags from swizzled Vt with the SAME permuted-kv mapping
    const char* Vb = Vs + buf * 8192;
    const int sub = (l4 & 1) * 8;
#pragma unroll
    for (int kk = 0; kk < 2; ++kk) {
      const int cr0 = kk * 4 + (l4 >> 1);
#pragma unroll
      for (int fd = 0; fd < 4; ++fd) {
        const int d = fd * 16 + l15;
        const char* row = Vb + d * 128;
        bf16x4 lo = *(const bf16x4*)(row + ((cr0 ^ (d & 7)) << 4) + sub);
        bf16x4 hi = *(const bf16x4*)(row + (((cr0 + 2) ^ (d & 7)) << 4) + sub);
        bf16x8 vb = __builtin_shufflevector(lo, hi, 0, 1, 2, 3, 4, 5, 6, 7);
        o[fd] = __builtin_amdgcn_mfma_f32_16x16x32_bf16(pa[kk], vb, o[fd], 0, 0, 0);
      }
    }

    // cross-lane row-sum after PV issue (overlaps matrix pipe)
    rs += __shfl_xor(rs, 16);
    rs += __shfl_xor(rs, 32);
    lsum += rs;

    // (d) late-write next V tile into the other buffer
    if (t < 31) vt_write(Vs + (buf ^ 1) * 8192, nv0, nv1);

    __syncthreads();  // all waves' writes visible before next tile's reads
  }

  // normalize + store (row = q0 + w*16 + l4*4 + r, col = h64 + fd*16 + l15)
  const float inv = 1.0f / lsum;
  f32x4 iv;
#pragma unroll
  for (int r = 0; r < 4; ++r) iv[r] = __shfl(inv, l4 * 4 + r);
  bf16* op = O + ((long)(b * 2048 + q0 + w * 16 + l4 * 4)) * 768 + h64 + l15;
#pragma unroll
  for (int fd = 0; fd < 4; ++fd)
#pragma unroll
    for (int r = 0; r < 4; ++r)
      op[(long)r * 768 + fd * 16] = (bf16)(o[fd][r] * iv[r]);
}

// ---------------- launch ----------------
extern "C" void kernel_launch(void* const* d_in, const int* in_sizes, int n_in,
                              void* d_out, int out_size, void* d_ws, size_t ws_size,
                              hipStream_t stream) {
  const float* x  = (const float*)d_in[0];
  const float* wq = (const float*)d_in[1];
  const float* wp = (const float*)d_in[2];
  float* out = (float*)d_out;
  char* ws = (char*)d_ws;

  bf16* xb   = (bf16*)(ws + 0);
  bf16* wqb  = (bf16*)(ws + 6291456);
  bf16* wpb  = (bf16*)(ws + 9830400);
  bf16* qkvb = (bf16*)(ws + 11010048);
  bf16* ob   = (bf16*)(ws + 29884416);

  cvt3<<<dim3(1024), dim3(256), 0, stream>>>(x, wq, wp, xb, wqb, wpb);
  // qkv = x @ Wqkv^T : M=4096 N=2304 K=768
  gemm_nt<bf16><<<dim3(576), dim3(256), 0, stream>>>(xb, wqb, qkvb, 768, 768, 768, 2304, 32);
  attn_fwd<<<dim3(32, 24), dim3(256), 0, stream>>>(qkvb, ob);
  // out = attn_out @ Wproj^T : M=4096 N=768 K=768, fp32 out
  gemm_nt<float><<<dim3(192), dim3(256), 0, stream>>>(ob, wpb, out, 768, 768, 768, 768, 32);
}